// Round 12
// baseline (360.426 us; speedup 1.0000x reference)
//
#include <hip/hip_runtime.h>

#define NN 100000
#define NE 1600000
#define DI 128
#define DH 128
#define DO 64
#define NN16 ((size_t)NN * 16)
#define NBK 391           // buckets of 256 nodes (dst >> 8)
#define SLOT 5120         // per-bucket slot capacity
#define PAD 16            // one counter per 64B line
#define EPB 8192          // edges per scatter block
#define NSB ((NE + EPB - 1) / EPB)  // 196

typedef unsigned int uint;
typedef unsigned short ushort;
typedef __bf16 bf16x8 __attribute__((ext_vector_type(8)));
typedef float f32x4 __attribute__((ext_vector_type(4)));

// ---- bf16 helpers (manual, RTNE) ----
__device__ __forceinline__ float bf_lo(uint u) { return __uint_as_float(u << 16); }
__device__ __forceinline__ float bf_hi(uint u) { return __uint_as_float(u & 0xffff0000u); }
__device__ __forceinline__ ushort f2bf(float f) {
    uint u = __float_as_uint(f);
    uint r = u + 0x7fffu + ((u >> 16) & 1u);
    return (ushort)(r >> 16);
}

// ---- prep: bucket cursor init + weight transposes + deg-hist zero ----
__global__ void k_prep(const float* __restrict__ W1, const float* __restrict__ W2,
                       ushort* __restrict__ w1t, ushort* __restrict__ w2t,
                       int* __restrict__ bcur, int* __restrict__ dcnt) {
    int t = blockIdx.x * 256 + threadIdx.x;
    if (t < NBK) bcur[t * PAD] = t * SLOT;
    if (t < 64) dcnt[t] = 0;
    if (t < 128 * 128) {
        int c = t >> 7, k = t & 127;
        w1t[t] = f2bf(W1[k * 128 + c]);
    } else if (t < 128 * 128 + 64 * 128) {
        int u = t - 128 * 128;
        int c = u >> 7, k = u & 127;
        w2t[u] = f2bf(W2[k * 64 + c]);
    }
}

// ---- staged bucket scatter: LDS counting sort per 8192-edge block ----
__global__ __launch_bounds__(512) void k_bscatter(const int* __restrict__ src,
                                                  const int* __restrict__ dst,
                                                  int* __restrict__ bcur,
                                                  uint* __restrict__ ebuf) {
    __shared__ uint stage[EPB];        // 32 KB
    __shared__ ushort bktid[EPB];      // 16 KB
    __shared__ int lcnt[NBK];
    __shared__ int loff[NBK];
    __shared__ int gbase[NBK];
    __shared__ int s[512];
    int t = threadIdx.x;
    int e0 = blockIdx.x * EPB;
    int n = min(EPB, NE - e0);
    for (int i = t; i < NBK; i += 512) lcnt[i] = 0;
    __syncthreads();
    for (int i = t; i < n; i += 512)
        atomicAdd(&lcnt[dst[e0 + i] >> 8], 1);
    __syncthreads();
    int myc = (t < NBK) ? lcnt[t] : 0;
    s[t] = myc;
    __syncthreads();
    for (int d = 1; d < 512; d <<= 1) {
        int a = (t >= d) ? s[t - d] : 0;
        __syncthreads();
        s[t] += a;
        __syncthreads();
    }
    if (t < NBK) {
        loff[t] = s[t] - myc;
        gbase[t] = atomicAdd(&bcur[t * PAD], myc);
        lcnt[t] = s[t] - myc;
    }
    __syncthreads();
    for (int i = t; i < n; i += 512) {
        int d = dst[e0 + i];
        int sv = src[e0 + i];
        int b = d >> 8;
        int p = atomicAdd(&lcnt[b], 1);
        stage[p] = ((uint)sv << 8) | (uint)(d & 255);
        bktid[p] = (ushort)b;
    }
    __syncthreads();
    for (int j = t; j < n; j += 512) {
        int b = bktid[j];
        ebuf[gbase[b] + (j - loff[b])] = stage[j];
    }
}

// ---- per-bucket (256 nodes) hist + scan + fill; emits offdeg, inv, csr, deg-hist ----
__global__ __launch_bounds__(256) void k_bfill(const uint* __restrict__ ebuf,
                                               const int* __restrict__ bcur,
                                               uint2* __restrict__ offdeg,
                                               float* __restrict__ inv,
                                               int* __restrict__ csr_src,
                                               int* __restrict__ dcnt) {
    __shared__ int cnt[256];
    __shared__ int s[256];
    __shared__ int cur[256];
    __shared__ int dh[64];
    int b = blockIdx.x, t = threadIdx.x;
    int ebeg = b * SLOT;
    int eend = bcur[b * PAD];
    cnt[t] = 0;
    if (t < 64) dh[t] = 0;
    __syncthreads();
    for (int e = ebeg + t; e < eend; e += 256)
        atomicAdd(&cnt[ebuf[e] & 255], 1);
    __syncthreads();
    int v = cnt[t];
    s[t] = v;
    __syncthreads();
    for (int d = 1; d < 256; d <<= 1) {
        int a = (t >= d) ? s[t - d] : 0;
        __syncthreads();
        s[t] += a;
        __syncthreads();
    }
    int beg = ebeg + s[t] - v;
    int node = b * 256 + t;
    if (node < NN) {
        offdeg[node] = make_uint2((uint)beg, (uint)v);
        inv[node] = rsqrtf((float)v + 1.0f);
        atomicAdd(&dh[min(v, 63)], 1);
    }
    cur[t] = beg;
    __syncthreads();
    if (t < 64 && dh[t]) atomicAdd(&dcnt[t], dh[t]);
    for (int e = ebeg + t; e < eend; e += 256) {
        uint ed = ebuf[e];
        int p = atomicAdd(&cur[ed & 255], 1);
        csr_src[p] = (int)(ed >> 8);
    }
}

// ---- scan 64 deg-bins -> dbase cursors ----
__global__ void k_dscan(const int* __restrict__ dcnt, int* __restrict__ dbase) {
    int t = threadIdx.x;  // 64
    int v = dcnt[t];
    int e = v;
    for (int d = 1; d < 64; d <<= 1) {
        int o = __shfl_up(e, d);
        if (t >= d) e += o;
    }
    dbase[t] = e - v;  // exclusive
}

// ---- fill deg-sorted node permutation ----
__global__ __launch_bounds__(256) void k_permfill(const uint2* __restrict__ offdeg,
                                                  int* __restrict__ dbase,
                                                  int* __restrict__ perm) {
    __shared__ int h[64];
    __shared__ int base[64];
    int t = threadIdx.x;
    int node = blockIdx.x * 256 + t;
    bool valid = node < NN;
    int d = valid ? min((int)offdeg[node].y, 63) : 0;
    if (t < 64) h[t] = 0;
    __syncthreads();
    int slot = 0;
    if (valid) slot = atomicAdd(&h[d], 1);
    __syncthreads();
    if (t < 64 && h[t]) base[t] = atomicAdd(&dbase[t], h[t]);
    __syncthreads();
    if (valid) perm[base[d] + slot] = node;
}

// ---------------- MFMA GEMM: one wave = 32 rows x N cols, K=128 ----------------
// A: fp32 row-major (ABF16=false) or bf16 slice-major [8][NN][16] (ABF16=true)
// out: bf16 slice-major [N/16][NN][16], row r scaled by inv[r]
template <int N, bool ABF16>
__global__ __launch_bounds__(256) void k_gemm_mfma(const void* __restrict__ Ap,
                                                   const ushort* __restrict__ Wt,
                                                   const float* __restrict__ inv,
                                                   ushort* __restrict__ out) {
    int wid = threadIdx.x >> 6;
    int lane = threadIdx.x & 63;
    int r0 = (blockIdx.x * 4 + wid) * 32;
    if (r0 >= NN) return;
    int rlo = lane & 15, khi = lane >> 4;  // khi in 0..3

    constexpr int CT = N / 16;  // 8 (N=128) or 4 (N=64)
    f32x4 acc[2][CT] = {};

#pragma unroll
    for (int ks = 0; ks < 4; ++ks) {
        bf16x8 bf[CT];
#pragma unroll
        for (int ct = 0; ct < CT; ++ct)
            bf[ct] = *(const bf16x8*)(Wt + (ct * 16 + rlo) * 128 + ks * 32 + khi * 8);
#pragma unroll
        for (int rt = 0; rt < 2; ++rt) {
            int row = r0 + rt * 16 + rlo;
            bf16x8 af;
            if (ABF16) {
                const ushort* As = (const ushort*)Ap;
                af = *(const bf16x8*)(As + (size_t)(2 * ks + (khi >> 1)) * NN16 +
                                      (size_t)row * 16 + (khi & 1) * 8);
            } else {
                const float* pa = (const float*)Ap + (size_t)row * 128 + ks * 32 + khi * 8;
                float4 f0 = *(const float4*)pa;
                float4 f1 = *(const float4*)(pa + 4);
                af[0] = (__bf16)f0.x; af[1] = (__bf16)f0.y;
                af[2] = (__bf16)f0.z; af[3] = (__bf16)f0.w;
                af[4] = (__bf16)f1.x; af[5] = (__bf16)f1.y;
                af[6] = (__bf16)f1.z; af[7] = (__bf16)f1.w;
            }
#pragma unroll
            for (int ct = 0; ct < CT; ++ct)
                acc[rt][ct] = __builtin_amdgcn_mfma_f32_16x16x32_bf16(af, bf[ct], acc[rt][ct], 0, 0, 0);
        }
    }
#pragma unroll
    for (int rt = 0; rt < 2; ++rt) {
        int rowb = r0 + rt * 16 + 4 * khi;
#pragma unroll
        for (int b = 0; b < 4; ++b) {
            float sc = inv[rowb + b];
#pragma unroll
            for (int ct = 0; ct < CT; ++ct)
                out[(size_t)ct * NN16 + (size_t)(rowb + b) * 16 + rlo] = f2bf(acc[rt][ct][b] * sc);
        }
    }
}

// ---- 16-feat accumulate of one table row (2x uint4) into a[16] ----
#define ACC16(L, H)                                                   \
    do {                                                              \
        a[0] += bf_lo((L).x);  a[1] += bf_hi((L).x);                  \
        a[2] += bf_lo((L).y);  a[3] += bf_hi((L).y);                  \
        a[4] += bf_lo((L).z);  a[5] += bf_hi((L).z);                  \
        a[6] += bf_lo((L).w);  a[7] += bf_hi((L).w);                  \
        a[8] += bf_lo((H).x);  a[9] += bf_hi((H).x);                  \
        a[10] += bf_lo((H).y); a[11] += bf_hi((H).y);                 \
        a[12] += bf_lo((H).z); a[13] += bf_hi((H).z);                 \
        a[14] += bf_lo((H).w); a[15] += bf_hi((H).w);                 \
    } while (0)

// ---------------- lane-per-node sliced aggregation, D=128 -> bf16 sliced out ----------------
// tab sliced [8][NN][16] bf16 (= inv[s]*h[s]); slice = blockIdx&7 (XCD-pinned).
// One lane owns one node: 16 fp32 accumulators, 32B row load per edge.
__global__ __launch_bounds__(256) void k_aggs128(const uint2* __restrict__ offdeg,
                                                 const int* __restrict__ perm,
                                                 const int* __restrict__ csr,
                                                 const ushort* __restrict__ tab,
                                                 const float* __restrict__ inv,
                                                 const float* __restrict__ bias,
                                                 ushort* __restrict__ outb) {
    int slice = blockIdx.x & 7;
    int i = (blockIdx.x >> 3) * 256 + threadIdx.x;
    if (i >= NN) return;
    int node = perm[i];
    const uint4* t128 = (const uint4*)(tab + (size_t)slice * NN16);  // [NN][2]
    uint2 od = offdeg[node];
    int beg = (int)od.x, deg = (int)od.y;
    float a[16];
#pragma unroll
    for (int j = 0; j < 16; ++j) a[j] = 0.f;
    int k = 0;
    for (; k + 3 < deg; k += 4) {
        int s0 = csr[beg + k], s1 = csr[beg + k + 1];
        int s2 = csr[beg + k + 2], s3 = csr[beg + k + 3];
        uint4 l0 = t128[(size_t)s0 * 2], h0 = t128[(size_t)s0 * 2 + 1];
        uint4 l1 = t128[(size_t)s1 * 2], h1 = t128[(size_t)s1 * 2 + 1];
        uint4 l2 = t128[(size_t)s2 * 2], h2 = t128[(size_t)s2 * 2 + 1];
        uint4 l3 = t128[(size_t)s3 * 2], h3 = t128[(size_t)s3 * 2 + 1];
        ACC16(l0, h0); ACC16(l1, h1); ACC16(l2, h2); ACC16(l3, h3);
    }
    for (; k < deg; ++k) {
        int s0 = csr[beg + k];
        uint4 l0 = t128[(size_t)s0 * 2], h0 = t128[(size_t)s0 * 2 + 1];
        ACC16(l0, h0);
    }
    // self + scale + bias + relu + pack
    uint4 sl = t128[(size_t)node * 2], sh = t128[(size_t)node * 2 + 1];
    ACC16(sl, sh);
    float invd = inv[node];
    const float* bb = bias + slice * 16;
    uint4 o0, o1;
    float r0, r1;
    r0 = fmaxf(fmaf(invd, a[0], bb[0]), 0.f);  r1 = fmaxf(fmaf(invd, a[1], bb[1]), 0.f);
    o0.x = (uint)f2bf(r0) | ((uint)f2bf(r1) << 16);
    r0 = fmaxf(fmaf(invd, a[2], bb[2]), 0.f);  r1 = fmaxf(fmaf(invd, a[3], bb[3]), 0.f);
    o0.y = (uint)f2bf(r0) | ((uint)f2bf(r1) << 16);
    r0 = fmaxf(fmaf(invd, a[4], bb[4]), 0.f);  r1 = fmaxf(fmaf(invd, a[5], bb[5]), 0.f);
    o0.z = (uint)f2bf(r0) | ((uint)f2bf(r1) << 16);
    r0 = fmaxf(fmaf(invd, a[6], bb[6]), 0.f);  r1 = fmaxf(fmaf(invd, a[7], bb[7]), 0.f);
    o0.w = (uint)f2bf(r0) | ((uint)f2bf(r1) << 16);
    r0 = fmaxf(fmaf(invd, a[8], bb[8]), 0.f);  r1 = fmaxf(fmaf(invd, a[9], bb[9]), 0.f);
    o1.x = (uint)f2bf(r0) | ((uint)f2bf(r1) << 16);
    r0 = fmaxf(fmaf(invd, a[10], bb[10]), 0.f); r1 = fmaxf(fmaf(invd, a[11], bb[11]), 0.f);
    o1.y = (uint)f2bf(r0) | ((uint)f2bf(r1) << 16);
    r0 = fmaxf(fmaf(invd, a[12], bb[12]), 0.f); r1 = fmaxf(fmaf(invd, a[13], bb[13]), 0.f);
    o1.z = (uint)f2bf(r0) | ((uint)f2bf(r1) << 16);
    r0 = fmaxf(fmaf(invd, a[14], bb[14]), 0.f); r1 = fmaxf(fmaf(invd, a[15], bb[15]), 0.f);
    o1.w = (uint)f2bf(r0) | ((uint)f2bf(r1) << 16);
    uint4* ob = (uint4*)(outb + (size_t)slice * NN16);
    ob[(size_t)node * 2] = o0;
    ob[(size_t)node * 2 + 1] = o1;
}

// ---------------- lane-per-node sliced aggregation, D=64 -> fp32 row-major out ----------------
// tab2 sliced [4][NN][16] bf16; slice = blockIdx&3.
__global__ __launch_bounds__(256) void k_aggs64(const uint2* __restrict__ offdeg,
                                                const int* __restrict__ perm,
                                                const int* __restrict__ csr,
                                                const ushort* __restrict__ tab,
                                                const float* __restrict__ inv,
                                                const float* __restrict__ bias,
                                                float* __restrict__ out) {
    int slice = blockIdx.x & 3;
    int i = (blockIdx.x >> 2) * 256 + threadIdx.x;
    if (i >= NN) return;
    int node = perm[i];
    const uint4* t128 = (const uint4*)(tab + (size_t)slice * NN16);  // [NN][2]
    uint2 od = offdeg[node];
    int beg = (int)od.x, deg = (int)od.y;
    float a[16];
#pragma unroll
    for (int j = 0; j < 16; ++j) a[j] = 0.f;
    int k = 0;
    for (; k + 3 < deg; k += 4) {
        int s0 = csr[beg + k], s1 = csr[beg + k + 1];
        int s2 = csr[beg + k + 2], s3 = csr[beg + k + 3];
        uint4 l0 = t128[(size_t)s0 * 2], h0 = t128[(size_t)s0 * 2 + 1];
        uint4 l1 = t128[(size_t)s1 * 2], h1 = t128[(size_t)s1 * 2 + 1];
        uint4 l2 = t128[(size_t)s2 * 2], h2 = t128[(size_t)s2 * 2 + 1];
        uint4 l3 = t128[(size_t)s3 * 2], h3 = t128[(size_t)s3 * 2 + 1];
        ACC16(l0, h0); ACC16(l1, h1); ACC16(l2, h2); ACC16(l3, h3);
    }
    for (; k < deg; ++k) {
        int s0 = csr[beg + k];
        uint4 l0 = t128[(size_t)s0 * 2], h0 = t128[(size_t)s0 * 2 + 1];
        ACC16(l0, h0);
    }
    uint4 sl = t128[(size_t)node * 2], sh = t128[(size_t)node * 2 + 1];
    ACC16(sl, sh);
    float invd = inv[node];
    const float* bb = bias + slice * 16;
    float4 r[4];
#pragma unroll
    for (int q = 0; q < 4; ++q) {
        r[q].x = fmaf(invd, a[q * 4 + 0], bb[q * 4 + 0]);
        r[q].y = fmaf(invd, a[q * 4 + 1], bb[q * 4 + 1]);
        r[q].z = fmaf(invd, a[q * 4 + 2], bb[q * 4 + 2]);
        r[q].w = fmaf(invd, a[q * 4 + 3], bb[q * 4 + 3]);
    }
    float4* po = (float4*)(out + (size_t)node * 64 + slice * 16);
#pragma unroll
    for (int q = 0; q < 4; ++q) po[q] = r[q];
}

extern "C" void kernel_launch(void* const* d_in, const int* in_sizes, int n_in,
                              void* d_out, int out_size, void* d_ws, size_t ws_size,
                              hipStream_t stream) {
    const float* x  = (const float*)d_in[0];
    const int* ei   = (const int*)d_in[1];
    const int* src  = ei;        // edge_index[0]
    const int* dst  = ei + NE;   // edge_index[1]
    const float* W1 = (const float*)d_in[2];
    const float* b1 = (const float*)d_in[3];
    const float* W2 = (const float*)d_in[4];
    const float* b2 = (const float*)d_in[5];
    float* out = (float*)d_out;

    // workspace layout (16B alignment maintained)
    uint2*  offdeg  = (uint2*)d_ws;                      // NN uint2
    float*  inv     = (float*)(offdeg + NN);             // 100004 floats
    int*    bcur    = (int*)(inv + 100004);              // NBK*16 ints (padded)
    int*    dcnt    = bcur + NBK * PAD;                  // 64 ints
    int*    dbase   = dcnt + 64;                         // 64 ints
    int*    perm    = dbase + 64;                        // 100096 ints
    int*    csr_src = perm + 100096;                     // NBK*SLOT ints (slotted)
    ushort* w1t     = (ushort*)(csr_src + NBK * SLOT);   // 128*128 bf16
    ushort* w2t     = w1t + 128 * 128;                   // 64*128 bf16
    ushort* h       = w2t + 64 * 128;                    // [8][NN][16] bf16 (inv-scaled)
    ushort* hagg    = h + (size_t)NN * DH;               // [8][NN][16] bf16
    ushort* h2      = hagg + (size_t)NN * DH;            // [4][NN][16] bf16 (inv-scaled)
    uint*   ebuf    = (uint*)h2;                         // NBK*SLOT uint, aliases h2

    // prep + CSR build + deg-sorted perm
    k_prep<<<96, 256, 0, stream>>>(W1, W2, w1t, w2t, bcur, dcnt);
    k_bscatter<<<NSB, 512, 0, stream>>>(src, dst, bcur, ebuf);
    k_bfill<<<NBK, 256, 0, stream>>>(ebuf, bcur, offdeg, inv, csr_src, dcnt);
    k_dscan<<<1, 64, 0, stream>>>(dcnt, dbase);
    k_permfill<<<NBK, 256, 0, stream>>>(offdeg, dbase, perm);

    // layer 1: h = slice8(inv .* (x @ W1)) ; hagg = slice8(relu(inv.*(sum+self)+b1))
    k_gemm_mfma<DH, false><<<(NN + 127) / 128, 256, 0, stream>>>(x, w1t, inv, h);
    k_aggs128<<<NBK * 8, 256, 0, stream>>>(offdeg, perm, csr_src, h, inv, b1, hagg);

    // layer 2: h2 = slice4(inv .* (hagg @ W2)) ; out = inv.*(sum+self) + b2 (fp32)
    k_gemm_mfma<DO, true><<<(NN + 127) / 128, 256, 0, stream>>>(hagg, w2t, inv, h2);
    k_aggs64<<<NBK * 4, 256, 0, stream>>>(offdeg, perm, csr_src, h2, inv, b2, out);
}

// Round 13
// 246.731 us; speedup vs baseline: 1.4608x; 1.4608x over previous
//
#include <hip/hip_runtime.h>

#define NN 100000
#define NE 1600000
#define DI 128
#define DH 128
#define DO 64
#define NN16 ((size_t)NN * 16)
#define NBK 391           // buckets of 256 nodes (dst >> 8)
#define SLOT 5120         // per-bucket slot capacity
#define PAD 16            // one counter per 64B line
#define EPB 8192          // edges per scatter block
#define NSB ((NE + EPB - 1) / EPB)  // 196

typedef unsigned int uint;
typedef unsigned short ushort;
typedef __bf16 bf16x8 __attribute__((ext_vector_type(8)));
typedef float f32x4 __attribute__((ext_vector_type(4)));

// ---- bf16 helpers (manual, RTNE) ----
__device__ __forceinline__ float bf_lo(uint u) { return __uint_as_float(u << 16); }
__device__ __forceinline__ float bf_hi(uint u) { return __uint_as_float(u & 0xffff0000u); }
__device__ __forceinline__ ushort f2bf(float f) {
    uint u = __float_as_uint(f);
    uint r = u + 0x7fffu + ((u >> 16) & 1u);
    return (ushort)(r >> 16);
}

// ---- prep: bucket cursor init + weight transposes ----
__global__ void k_prep(const float* __restrict__ W1, const float* __restrict__ W2,
                       ushort* __restrict__ w1t, ushort* __restrict__ w2t,
                       int* __restrict__ bcur) {
    int t = blockIdx.x * 256 + threadIdx.x;
    if (t < NBK) bcur[t * PAD] = t * SLOT;
    if (t < 128 * 128) {
        int c = t >> 7, k = t & 127;
        w1t[t] = f2bf(W1[k * 128 + c]);
    } else if (t < 128 * 128 + 64 * 128) {
        int u = t - 128 * 128;
        int c = u >> 7, k = u & 127;
        w2t[u] = f2bf(W2[k * 64 + c]);
    }
}

// ---- staged bucket scatter: LDS counting sort per 8192-edge block ----
__global__ __launch_bounds__(512) void k_bscatter(const int* __restrict__ src,
                                                  const int* __restrict__ dst,
                                                  int* __restrict__ bcur,
                                                  uint* __restrict__ ebuf) {
    __shared__ uint stage[EPB];        // 32 KB
    __shared__ ushort bktid[EPB];      // 16 KB
    __shared__ int lcnt[NBK];
    __shared__ int loff[NBK];
    __shared__ int gbase[NBK];
    __shared__ int s[512];
    int t = threadIdx.x;
    int e0 = blockIdx.x * EPB;
    int n = min(EPB, NE - e0);
    for (int i = t; i < NBK; i += 512) lcnt[i] = 0;
    __syncthreads();
    for (int i = t; i < n; i += 512)
        atomicAdd(&lcnt[dst[e0 + i] >> 8], 1);
    __syncthreads();
    int myc = (t < NBK) ? lcnt[t] : 0;
    s[t] = myc;
    __syncthreads();
    for (int d = 1; d < 512; d <<= 1) {
        int a = (t >= d) ? s[t - d] : 0;
        __syncthreads();
        s[t] += a;
        __syncthreads();
    }
    if (t < NBK) {
        loff[t] = s[t] - myc;
        gbase[t] = atomicAdd(&bcur[t * PAD], myc);
        lcnt[t] = s[t] - myc;
    }
    __syncthreads();
    for (int i = t; i < n; i += 512) {
        int d = dst[e0 + i];
        int sv = src[e0 + i];
        int b = d >> 8;
        int p = atomicAdd(&lcnt[b], 1);
        stage[p] = ((uint)sv << 8) | (uint)(d & 255);
        bktid[p] = (ushort)b;
    }
    __syncthreads();
    for (int j = t; j < n; j += 512) {
        int b = bktid[j];
        ebuf[gbase[b] + (j - loff[b])] = stage[j];
    }
}

// ---- per-bucket (256 nodes) hist + scan + fill; emits offdeg, inv, csr ----
__global__ __launch_bounds__(256) void k_bfill(const uint* __restrict__ ebuf,
                                               const int* __restrict__ bcur,
                                               uint2* __restrict__ offdeg,
                                               float* __restrict__ inv,
                                               int* __restrict__ csr_src) {
    __shared__ int cnt[256];
    __shared__ int s[256];
    __shared__ int cur[256];
    int b = blockIdx.x, t = threadIdx.x;
    int ebeg = b * SLOT;
    int eend = bcur[b * PAD];
    cnt[t] = 0;
    __syncthreads();
    for (int e = ebeg + t; e < eend; e += 256)
        atomicAdd(&cnt[ebuf[e] & 255], 1);
    __syncthreads();
    int v = cnt[t];
    s[t] = v;
    __syncthreads();
    for (int d = 1; d < 256; d <<= 1) {
        int a = (t >= d) ? s[t - d] : 0;
        __syncthreads();
        s[t] += a;
        __syncthreads();
    }
    int beg = ebeg + s[t] - v;
    int node = b * 256 + t;
    if (node < NN) {
        offdeg[node] = make_uint2((uint)beg, (uint)v);
        inv[node] = rsqrtf((float)v + 1.0f);
    }
    cur[t] = beg;
    __syncthreads();
    for (int e = ebeg + t; e < eend; e += 256) {
        uint ed = ebuf[e];
        int p = atomicAdd(&cur[ed & 255], 1);
        csr_src[p] = (int)(ed >> 8);
    }
}

// ---------------- MFMA GEMM: one wave = 32 rows x N cols, K=128 ----------------
// A: fp32 row-major (ABF16=false) or bf16 slice-major [8][NN][16] (ABF16=true)
// out: bf16 slice-major [N/16][NN][16], row r scaled by inv[r]
template <int N, bool ABF16>
__global__ __launch_bounds__(256) void k_gemm_mfma(const void* __restrict__ Ap,
                                                   const ushort* __restrict__ Wt,
                                                   const float* __restrict__ inv,
                                                   ushort* __restrict__ out) {
    int wid = threadIdx.x >> 6;
    int lane = threadIdx.x & 63;
    int r0 = (blockIdx.x * 4 + wid) * 32;
    if (r0 >= NN) return;
    int rlo = lane & 15, khi = lane >> 4;  // khi in 0..3

    constexpr int CT = N / 16;  // 8 (N=128) or 4 (N=64)
    f32x4 acc[2][CT] = {};

#pragma unroll
    for (int ks = 0; ks < 4; ++ks) {
        bf16x8 bf[CT];
#pragma unroll
        for (int ct = 0; ct < CT; ++ct)
            bf[ct] = *(const bf16x8*)(Wt + (ct * 16 + rlo) * 128 + ks * 32 + khi * 8);
#pragma unroll
        for (int rt = 0; rt < 2; ++rt) {
            int row = r0 + rt * 16 + rlo;
            bf16x8 af;
            if (ABF16) {
                const ushort* As = (const ushort*)Ap;
                af = *(const bf16x8*)(As + (size_t)(2 * ks + (khi >> 1)) * NN16 +
                                      (size_t)row * 16 + (khi & 1) * 8);
            } else {
                const float* pa = (const float*)Ap + (size_t)row * 128 + ks * 32 + khi * 8;
                float4 f0 = *(const float4*)pa;
                float4 f1 = *(const float4*)(pa + 4);
                af[0] = (__bf16)f0.x; af[1] = (__bf16)f0.y;
                af[2] = (__bf16)f0.z; af[3] = (__bf16)f0.w;
                af[4] = (__bf16)f1.x; af[5] = (__bf16)f1.y;
                af[6] = (__bf16)f1.z; af[7] = (__bf16)f1.w;
            }
#pragma unroll
            for (int ct = 0; ct < CT; ++ct)
                acc[rt][ct] = __builtin_amdgcn_mfma_f32_16x16x32_bf16(af, bf[ct], acc[rt][ct], 0, 0, 0);
        }
    }
#pragma unroll
    for (int rt = 0; rt < 2; ++rt) {
        int rowb = r0 + rt * 16 + 4 * khi;
#pragma unroll
        for (int b = 0; b < 4; ++b) {
            float sc = inv[rowb + b];
#pragma unroll
            for (int ct = 0; ct < CT; ++ct)
                out[(size_t)ct * NN16 + (size_t)(rowb + b) * 16 + rlo] = f2bf(acc[rt][ct][b] * sc);
        }
    }
}

// ---------------- sliced aggregation, shfl-broadcast gather ----------------
// 8-lane group owns one node at a time (16 feats, 2 per lane). Per round the
// group loads 8 csr indices coalesced (lane u -> edge r+u), shfl-broadcasts
// each, and issues 8 INDEPENDENT 4B row-gathers. slice = blockIdx&(NS-1),
// XCD-pinned so the 3.2MB slice stays L2-resident (round-11-proven pattern).
template <int NS, bool RELU, bool F32OUT>
__global__ __launch_bounds__(256) void k_aggs(const uint2* __restrict__ offdeg,
                                              const int* __restrict__ csr,
                                              const ushort* __restrict__ tab,
                                              const float* __restrict__ inv,
                                              const float* __restrict__ bias,
                                              void* __restrict__ outp) {
    int slice = blockIdx.x & (NS - 1);
    int nb = blockIdx.x / NS;
    int lane = threadIdx.x & 63;
    int wid = threadIdx.x >> 6;
    int g = lane >> 3;   // group 0..7
    int u = lane & 7;    // uint (2 feats) within row
    const uint* t32 = (const uint*)tab + (size_t)slice * (NN * 8);
    float2 bb = *(const float2*)(bias + slice * 16 + u * 2);
#pragma unroll
    for (int j = 0; j < 8; ++j) {
        int node = nb * 256 + wid * 64 + j * 8 + g;  // groups cover 8 consecutive nodes
        if (node >= NN) continue;
        uint2 od = offdeg[node];
        int beg = (int)od.x, deg = (int)od.y;
        float a0 = 0.f, a1 = 0.f;
        int full = deg & ~7;
        int r = 0;
        for (; r < full; r += 8) {
            int sidx = csr[beg + r + u];
#pragma unroll
            for (int e = 0; e < 8; ++e) {
                int se = __shfl(sidx, (g << 3) + e);
                uint uu = t32[(size_t)se * 8 + u];
                a0 += bf_lo(uu); a1 += bf_hi(uu);
            }
        }
        int rem = deg - full;
        if (rem) {
            int sidx = csr[beg + min(r + u, deg - 1)];
#pragma unroll
            for (int e = 0; e < 8; ++e) {
                if (e < rem) {
                    int se = __shfl(sidx, (g << 3) + e);
                    uint uu = t32[(size_t)se * 8 + u];
                    a0 += bf_lo(uu); a1 += bf_hi(uu);
                }
            }
        }
        // self term
        uint su = t32[(size_t)node * 8 + u];
        a0 += bf_lo(su); a1 += bf_hi(su);
        float invd = inv[node];
        float r0 = fmaf(invd, a0, bb.x);
        float r1 = fmaf(invd, a1, bb.y);
        if (RELU) { r0 = fmaxf(r0, 0.f); r1 = fmaxf(r1, 0.f); }
        if (F32OUT) {
            // fp32 row-major [NN][64], slice covers feats slice*16..+15
            float* out = (float*)outp;
            *(float2*)(out + (size_t)node * 64 + slice * 16 + u * 2) = make_float2(r0, r1);
        } else {
            // bf16 slice-major [NS][NN][16]
            uint* o32 = (uint*)outp + (size_t)slice * (NN * 8);
            o32[(size_t)node * 8 + u] = (uint)f2bf(r0) | ((uint)f2bf(r1) << 16);
        }
    }
}

extern "C" void kernel_launch(void* const* d_in, const int* in_sizes, int n_in,
                              void* d_out, int out_size, void* d_ws, size_t ws_size,
                              hipStream_t stream) {
    const float* x  = (const float*)d_in[0];
    const int* ei   = (const int*)d_in[1];
    const int* src  = ei;        // edge_index[0]
    const int* dst  = ei + NE;   // edge_index[1]
    const float* W1 = (const float*)d_in[2];
    const float* b1 = (const float*)d_in[3];
    const float* W2 = (const float*)d_in[4];
    const float* b2 = (const float*)d_in[5];
    float* out = (float*)d_out;

    // workspace layout (16B alignment maintained)
    uint2*  offdeg  = (uint2*)d_ws;                      // NN uint2
    float*  inv     = (float*)(offdeg + NN);             // 100004 floats
    int*    bcur    = (int*)(inv + 100004);              // NBK*16 ints (padded)
    int*    csr_src = bcur + NBK * PAD;                  // NBK*SLOT ints (slotted)
    ushort* w1t     = (ushort*)(csr_src + NBK * SLOT);   // 128*128 bf16
    ushort* w2t     = w1t + 128 * 128;                   // 64*128 bf16
    ushort* h       = w2t + 64 * 128;                    // [8][NN][16] bf16 (inv-scaled)
    ushort* hagg    = h + (size_t)NN * DH;               // [8][NN][16] bf16
    ushort* h2      = hagg + (size_t)NN * DH;            // [4][NN][16] bf16 (inv-scaled)
    uint*   ebuf    = (uint*)h2;                         // NBK*SLOT uint, aliases h2

    // prep + CSR build
    k_prep<<<96, 256, 0, stream>>>(W1, W2, w1t, w2t, bcur);
    k_bscatter<<<NSB, 512, 0, stream>>>(src, dst, bcur, ebuf);
    k_bfill<<<NBK, 256, 0, stream>>>(ebuf, bcur, offdeg, inv, csr_src);

    // layer 1: h = slice8(inv .* (x @ W1)) ; hagg = slice8(relu(inv.*(sum+self)+b1))
    k_gemm_mfma<DH, false><<<(NN + 127) / 128, 256, 0, stream>>>(x, w1t, inv, h);
    k_aggs<8, true, false><<<NBK * 8, 256, 0, stream>>>(offdeg, csr_src, h, inv, b1, hagg);

    // layer 2: h2 = slice4(inv .* (hagg @ W2)) ; out = inv.*(sum+self) + b2 (fp32)
    k_gemm_mfma<DO, true><<<(NN + 127) / 128, 256, 0, stream>>>(hagg, w2t, inv, h2);
    k_aggs<4, false, true><<<NBK * 4, 256, 0, stream>>>(offdeg, csr_src, h2, inv, b2, out);
}